// Round 1
// baseline (2448.272 us; speedup 1.0000x reference)
//
#include <hip/hip_runtime.h>
#include <hip/hip_bf16.h>
#include <cstdint>
#include <cstddef>

// SlotAttentionV2 forward, MI355X.
// K1: LN + K/V projection (bf16 out to workspace).
// K2: one block per batch: reparam, 3 slot-attention iterations, GRU, MLP, KL.
// Workspace: K (B*N*64 bf16) + V (B*N*64 bf16) = 268 MB.

#define B_   256
#define N_   4096
#define NS_  8
#define D_   64
#define EPS_   1e-8f
#define SCALE_ 0.125f
#define OUT_SLOTS_ (B_ * NS_ * D_)   // 131072

typedef unsigned short u16;
typedef unsigned int   u32;

__device__ inline float bf2f(u16 u) {
  union { u32 i; float f; } c; c.i = ((u32)u) << 16; return c.f;
}
__device__ inline u16 f2bf(float f) {
  union { u32 i; float f; } c; c.f = f;
  return (u16)((c.i + 0x7fffu + ((c.i >> 16) & 1u)) >> 16);
}
__device__ inline void bf2x2(u32 u, float& lo, float& hi) {
  union { u32 i; float f; } a, b;
  a.i = u << 16; b.i = u & 0xffff0000u;
  lo = a.f; hi = b.f;
}
__device__ inline float wredsum(float v) {
  #pragma unroll
  for (int o = 32; o; o >>= 1) v += __shfl_xor(v, o, 64);
  return v;
}

// ---------------- Kernel 1: LN(inputs) -> K, V (bf16) ----------------
__global__ __launch_bounds__(256) void k_lnkv(
    const float* __restrict__ x,
    const float* __restrict__ ni_g, const float* __restrict__ ni_b,
    const float* __restrict__ Wk, const float* __restrict__ bk,
    const float* __restrict__ Wv, const float* __restrict__ bv,
    u16* __restrict__ K, u16* __restrict__ V)
{
  const int lane = threadIdx.x & 63;
  // lane h holds row h of Wk and Wv (contiguous 256B each) in registers.
  float wk[64], wv[64];
  {
    const float4* wkr = (const float4*)(Wk + lane * 64);
    const float4* wvr = (const float4*)(Wv + lane * 64);
    #pragma unroll
    for (int c = 0; c < 16; c++) {
      float4 a = wkr[c], b = wvr[c];
      wk[c*4+0] = a.x; wk[c*4+1] = a.y; wk[c*4+2] = a.z; wk[c*4+3] = a.w;
      wv[c*4+0] = b.x; wv[c*4+1] = b.y; wv[c*4+2] = b.z; wv[c*4+3] = b.w;
    }
  }
  const float gl = ni_g[lane], bl = ni_b[lane];
  const float bkl = bk[lane], bvl = bv[lane];
  const int  gwave = (int)((blockIdx.x * blockDim.x + threadIdx.x) >> 6);
  const int  nwave = (int)((gridDim.x * blockDim.x) >> 6);
  const long nrows = (long)B_ * N_;
  for (long row = gwave; row < nrows; row += nwave) {
    float xv = x[row * 64 + lane];
    float m  = wredsum(xv) * (1.0f / 64.0f);
    float c  = xv - m;
    float var = wredsum(c * c) * (1.0f / 64.0f);
    float rs = rsqrtf(var + 1e-5f);
    float xh = c * rs * gl + bl;
    float ak0 = bkl, ak1 = 0.f, av0 = bvl, av1 = 0.f;
    #pragma unroll
    for (int e = 0; e < 64; e += 2) {
      float xb0 = __shfl(xh, e, 64);
      float xb1 = __shfl(xh, e + 1, 64);
      ak0 = fmaf(xb0, wk[e],     ak0);
      av0 = fmaf(xb0, wv[e],     av0);
      ak1 = fmaf(xb1, wk[e + 1], ak1);
      av1 = fmaf(xb1, wv[e + 1], av1);
    }
    K[row * 64 + lane] = f2bf(ak0 + ak1);
    V[row * 64 + lane] = f2bf(av0 + av1);
  }
}

// ---------------- Kernel 2: block-per-batch slot attention ----------------
// LDS layout (dynamic, 86080 B):
//   attn  u16 [8][4096]   65536
//   q     f32 [8][64]      2048   (reused as LN buffer)
//   sl    f32 [8][64]      2048   (current slots)
//   sp    f32 [8][64]      2048   (slots_prev)
//   upd   f32 [8][64]      2048   (un-normalized updates)
//   prior f32 [8][128]     4096
//   hid   f32 [8][128]     4096
//   post  f32 [8][128]     4096
//   Ssum  f32 [8]            32
//   kl    f32 [8]            32
__global__ __launch_bounds__(512) void k_slot(
    const u16* __restrict__ K, const u16* __restrict__ V,
    const float* __restrict__ slots0, const float* __restrict__ prior_slots,
    const float* __restrict__ eps_noise,
    const float* __restrict__ npf_g, const float* __restrict__ npf_b,
    const float* __restrict__ Wq, const float* __restrict__ bq,
    const float* __restrict__ sr_W1, const float* __restrict__ sr_b1,
    const float* __restrict__ sr_W2, const float* __restrict__ sr_b2,
    const float* __restrict__ pr_W1, const float* __restrict__ pr_b1,
    const float* __restrict__ pr_W2, const float* __restrict__ pr_b2,
    const float* __restrict__ gWih, const float* __restrict__ gWhh,
    const float* __restrict__ gbih, const float* __restrict__ gbhh,
    const float* __restrict__ mW1, const float* __restrict__ mb1,
    const float* __restrict__ mW2, const float* __restrict__ mb2,
    float* __restrict__ out)
{
  extern __shared__ char smem[];
  u16*   attn_u  = (u16*)smem;                  // 65536
  float* q_f     = (float*)(smem + 65536);      // 2048
  float* sl_f    = (float*)(smem + 67584);      // 2048
  float* sp_f    = (float*)(smem + 69632);      // 2048
  float* upd_f   = (float*)(smem + 71680);      // 2048
  float* prior_f = (float*)(smem + 73728);      // 4096
  float* hid_f   = (float*)(smem + 77824);      // 4096
  float* post_f  = (float*)(smem + 81920);      // 4096
  float* Ssum    = (float*)(smem + 86016);      // 32
  float* kl_f    = (float*)(smem + 86048);      // 32

  const int tid  = threadIdx.x;
  const int wv   = tid >> 6;
  const int lane = tid & 63;
  const int b    = blockIdx.x;
  const u16* Kb = K + (size_t)b * (N_ * 64);
  const u16* Vb = V + (size_t)b * (N_ * 64);

  // ---- P0.1: load slots, prior hidden = relu(prior_slots @ pr_W1.T + pr_b1)
  sl_f[tid] = slots0[(size_t)b * 512 + tid];
  #pragma unroll
  for (int kk = 0; kk < 2; kk++) {
    int idx = tid + kk * 512;
    int s = idx >> 7, h = idx & 127;
    const float* xr = prior_slots + ((size_t)b * 8 + s) * 64;
    const float* wr = pr_W1 + h * 64;
    float a = pr_b1[h];
    #pragma unroll
    for (int ec = 0; ec < 16; ec++) {
      float4 xe = ((const float4*)xr)[ec];
      float4 w  = ((const float4*)wr)[ec];
      a = fmaf(xe.x, w.x, a); a = fmaf(xe.y, w.y, a);
      a = fmaf(xe.z, w.z, a); a = fmaf(xe.w, w.w, a);
    }
    hid_f[idx] = fmaxf(a, 0.f);
  }
  __syncthreads();
  // ---- P0.2: prior = hid @ pr_W2.T + pr_b2
  #pragma unroll
  for (int kk = 0; kk < 2; kk++) {
    int idx = tid + kk * 512;
    int s = idx >> 7, o = idx & 127;
    const float* hh = hid_f + s * 128;
    const float* wr = pr_W2 + o * 128;
    float a = pr_b2[o];
    #pragma unroll
    for (int ec = 0; ec < 32; ec++) {
      float4 xe = ((const float4*)hh)[ec];
      float4 w  = ((const float4*)wr)[ec];
      a = fmaf(xe.x, w.x, a); a = fmaf(xe.y, w.y, a);
      a = fmaf(xe.z, w.z, a); a = fmaf(xe.w, w.w, a);
    }
    prior_f[idx] = a;
  }
  __syncthreads();
  // ---- P0.3: sms hidden = relu(slots @ sr_W1.T + sr_b1)
  #pragma unroll
  for (int kk = 0; kk < 2; kk++) {
    int idx = tid + kk * 512;
    int s = idx >> 7, h = idx & 127;
    const float* xr = sl_f + s * 64;
    const float* wr = sr_W1 + h * 64;
    float a = sr_b1[h];
    #pragma unroll
    for (int ec = 0; ec < 16; ec++) {
      float4 xe = ((const float4*)xr)[ec];
      float4 w  = ((const float4*)wr)[ec];
      a = fmaf(xe.x, w.x, a); a = fmaf(xe.y, w.y, a);
      a = fmaf(xe.z, w.z, a); a = fmaf(xe.w, w.w, a);
    }
    hid_f[idx] = fmaxf(a, 0.f);
  }
  __syncthreads();
  // ---- P0.4: sms = hid @ sr_W2.T + sr_b2  -> post buffer
  #pragma unroll
  for (int kk = 0; kk < 2; kk++) {
    int idx = tid + kk * 512;
    int s = idx >> 7, o = idx & 127;
    const float* hh = hid_f + s * 128;
    const float* wr = sr_W2 + o * 128;
    float a = sr_b2[o];
    #pragma unroll
    for (int ec = 0; ec < 32; ec++) {
      float4 xe = ((const float4*)hh)[ec];
      float4 w  = ((const float4*)wr)[ec];
      a = fmaf(xe.x, w.x, a); a = fmaf(xe.y, w.y, a);
      a = fmaf(xe.z, w.z, a); a = fmaf(xe.w, w.w, a);
    }
    post_f[idx] = a;
  }
  __syncthreads();
  // ---- P0.5: reparam: slots = eps * exp(0.5*logvar) + mu
  {
    int s = wv, d = lane;
    float mu = post_f[s * 128 + d];
    float lv = post_f[s * 128 + 64 + d];
    sl_f[tid] = eps_noise[(size_t)b * 512 + tid] * __expf(0.5f * lv) + mu;
  }
  if (tid < 8) kl_f[tid] = 0.f;
  __syncthreads();

  // ---- iterations ----
  #pragma unroll 1
  for (int it = 0; it < 3; it++) {
    // I1: snapshot, zero accumulators, q = slots @ Wq.T + bq
    sp_f[tid]  = sl_f[tid];
    upd_f[tid] = 0.f;
    if (tid < 8) Ssum[tid] = 0.f;
    {
      int s = wv, d = lane;
      const float* xr = sl_f + s * 64;
      const float* wr = Wq + d * 64;
      float a = bq[d];
      #pragma unroll
      for (int ec = 0; ec < 16; ec++) {
        float4 xe = ((const float4*)xr)[ec];
        float4 w  = ((const float4*)wr)[ec];
        a = fmaf(xe.x, w.x, a); a = fmaf(xe.y, w.y, a);
        a = fmaf(xe.z, w.z, a); a = fmaf(xe.w, w.w, a);
      }
      q_f[tid] = a;
    }
    __syncthreads();

    // I2: pass A — per-pixel dots + softmax over slots (+EPS), 2 px/thread/step
    float s_loc[8];
    #pragma unroll
    for (int i = 0; i < 8; i++) s_loc[i] = 0.f;
    #pragma unroll 1
    for (int p = 0; p < 8; p += 2) {
      int j1 = p * 512 + tid;
      int j2 = j1 + 512;
      uint4 kr1[8], kr2[8];
      const uint4* p1 = (const uint4*)(Kb + (size_t)j1 * 64);
      const uint4* p2 = (const uint4*)(Kb + (size_t)j2 * 64);
      #pragma unroll
      for (int c = 0; c < 8; c++) { kr1[c] = p1[c]; kr2[c] = p2[c]; }
      float k1[64], k2[64];
      #pragma unroll
      for (int c = 0; c < 8; c++) {
        bf2x2(kr1[c].x, k1[c*8+0], k1[c*8+1]);
        bf2x2(kr1[c].y, k1[c*8+2], k1[c*8+3]);
        bf2x2(kr1[c].z, k1[c*8+4], k1[c*8+5]);
        bf2x2(kr1[c].w, k1[c*8+6], k1[c*8+7]);
        bf2x2(kr2[c].x, k2[c*8+0], k2[c*8+1]);
        bf2x2(kr2[c].y, k2[c*8+2], k2[c*8+3]);
        bf2x2(kr2[c].z, k2[c*8+4], k2[c*8+5]);
        bf2x2(kr2[c].w, k2[c*8+6], k2[c*8+7]);
      }
      float d1[8], d2[8];
      #pragma unroll
      for (int i = 0; i < 8; i++) {
        const float4* qr = (const float4*)(q_f + i * 64);  // broadcast
        float a1 = 0.f, a2 = 0.f;
        #pragma unroll
        for (int ec = 0; ec < 16; ec++) {
          float4 qv = qr[ec];
          a1 = fmaf(qv.x, k1[ec*4+0], a1);
          a1 = fmaf(qv.y, k1[ec*4+1], a1);
          a1 = fmaf(qv.z, k1[ec*4+2], a1);
          a1 = fmaf(qv.w, k1[ec*4+3], a1);
          a2 = fmaf(qv.x, k2[ec*4+0], a2);
          a2 = fmaf(qv.y, k2[ec*4+1], a2);
          a2 = fmaf(qv.z, k2[ec*4+2], a2);
          a2 = fmaf(qv.w, k2[ec*4+3], a2);
        }
        d1[i] = a1 * SCALE_;
        d2[i] = a2 * SCALE_;
      }
      float m1 = d1[0], m2 = d2[0];
      #pragma unroll
      for (int i = 1; i < 8; i++) { m1 = fmaxf(m1, d1[i]); m2 = fmaxf(m2, d2[i]); }
      float sm1 = 0.f, sm2 = 0.f;
      #pragma unroll
      for (int i = 0; i < 8; i++) {
        d1[i] = __expf(d1[i] - m1); sm1 += d1[i];
        d2[i] = __expf(d2[i] - m2); sm2 += d2[i];
      }
      float r1 = 1.0f / sm1, r2 = 1.0f / sm2;
      #pragma unroll
      for (int i = 0; i < 8; i++) {
        float a1 = fmaf(d1[i], r1, EPS_);
        float a2 = fmaf(d2[i], r2, EPS_);
        s_loc[i] += a1 + a2;
        attn_u[i * 4096 + j1] = f2bf(a1);
        attn_u[i * 4096 + j2] = f2bf(a2);
      }
    }
    #pragma unroll
    for (int i = 0; i < 8; i++) {
      float v = wredsum(s_loc[i]);
      if (lane == 0) atomicAdd(&Ssum[i], v);
    }
    __syncthreads();

    // I3: pass B — wave w covers j in [w*512, w*512+512); lane d accumulates
    // partial updates for ALL 8 slots at dim d.
    {
      float u[8];
      #pragma unroll
      for (int i = 0; i < 8; i++) u[i] = 0.f;
      const int jbase = wv * 512;
      #pragma unroll 2
      for (int jc = 0; jc < 64; jc++) {
        int j0 = jbase + jc * 8;
        float vvv[8];
        #pragma unroll
        for (int mm = 0; mm < 8; mm++)
          vvv[mm] = bf2f(Vb[(size_t)(j0 + mm) * 64 + lane]);
        #pragma unroll
        for (int i = 0; i < 8; i++) {
          uint4 au = *(const uint4*)(attn_u + i * 4096 + j0);  // broadcast
          float a0,a1,a2,a3,a4,a5,a6,a7;
          bf2x2(au.x, a0, a1); bf2x2(au.y, a2, a3);
          bf2x2(au.z, a4, a5); bf2x2(au.w, a6, a7);
          u[i] = fmaf(a0, vvv[0], u[i]); u[i] = fmaf(a1, vvv[1], u[i]);
          u[i] = fmaf(a2, vvv[2], u[i]); u[i] = fmaf(a3, vvv[3], u[i]);
          u[i] = fmaf(a4, vvv[4], u[i]); u[i] = fmaf(a5, vvv[5], u[i]);
          u[i] = fmaf(a6, vvv[6], u[i]); u[i] = fmaf(a7, vvv[7], u[i]);
        }
      }
      #pragma unroll
      for (int i = 0; i < 8; i++) atomicAdd(upd_f + i * 64 + lane, u[i]);
    }
    __syncthreads();

    // I4: GRU (1/S folded into gi scale) + I5: LN of GRU output (in-wave)
    {
      int s = wv, d = lane;
      const float* ur  = upd_f + s * 64;
      const float* hr  = sp_f + s * 64;
      const float* wi0 = gWih + d * 64;
      const float* wi1 = gWih + (64 + d) * 64;
      const float* wi2 = gWih + (128 + d) * 64;
      const float* wh0 = gWhh + d * 64;
      const float* wh1 = gWhh + (64 + d) * 64;
      const float* wh2 = gWhh + (128 + d) * 64;
      float air=0.f, aiz=0.f, ain=0.f, ahr=0.f, ahz=0.f, ahn=0.f;
      #pragma unroll
      for (int ec = 0; ec < 16; ec++) {
        float4 xe = ((const float4*)ur)[ec];
        float4 he = ((const float4*)hr)[ec];
        float4 w;
        w = ((const float4*)wi0)[ec];
        air = fmaf(xe.x,w.x,air); air = fmaf(xe.y,w.y,air);
        air = fmaf(xe.z,w.z,air); air = fmaf(xe.w,w.w,air);
        w = ((const float4*)wi1)[ec];
        aiz = fmaf(xe.x,w.x,aiz); aiz = fmaf(xe.y,w.y,aiz);
        aiz = fmaf(xe.z,w.z,aiz); aiz = fmaf(xe.w,w.w,aiz);
        w = ((const float4*)wi2)[ec];
        ain = fmaf(xe.x,w.x,ain); ain = fmaf(xe.y,w.y,ain);
        ain = fmaf(xe.z,w.z,ain); ain = fmaf(xe.w,w.w,ain);
        w = ((const float4*)wh0)[ec];
        ahr = fmaf(he.x,w.x,ahr); ahr = fmaf(he.y,w.y,ahr);
        ahr = fmaf(he.z,w.z,ahr); ahr = fmaf(he.w,w.w,ahr);
        w = ((const float4*)wh1)[ec];
        ahz = fmaf(he.x,w.x,ahz); ahz = fmaf(he.y,w.y,ahz);
        ahz = fmaf(he.z,w.z,ahz); ahz = fmaf(he.w,w.w,ahz);
        w = ((const float4*)wh2)[ec];
        ahn = fmaf(he.x,w.x,ahn); ahn = fmaf(he.y,w.y,ahn);
        ahn = fmaf(he.z,w.z,ahn); ahn = fmaf(he.w,w.w,ahn);
      }
      float sinv = 1.0f / Ssum[s];
      float rr = 1.0f / (1.0f + __expf(-(air * sinv + gbih[d]      + ahr + gbhh[d])));
      float zz = 1.0f / (1.0f + __expf(-(aiz * sinv + gbih[64 + d] + ahz + gbhh[64 + d])));
      float nn = tanhf(ain * sinv + gbih[128 + d] + rr * (ahn + gbhh[128 + d]));
      float hnew = (1.0f - zz) * nn + zz * sp_f[tid];
      sl_f[tid] = hnew;
      // LN(hnew) across the wave's 64 lanes (row s)
      float mm = wredsum(hnew) * (1.0f / 64.0f);
      float cc = hnew - mm;
      float va = wredsum(cc * cc) * (1.0f / 64.0f);
      q_f[tid] = cc * rsqrtf(va + 1e-5f) * npf_g[d] + npf_b[d];  // reuse q buffer
    }
    __syncthreads();

    // I6a: mlp hidden = relu(LN @ mW1.T + mb1)
    #pragma unroll
    for (int kk = 0; kk < 2; kk++) {
      int idx = tid + kk * 512;
      int s = idx >> 7, h = idx & 127;
      const float* xr = q_f + s * 64;
      const float* wr = mW1 + h * 64;
      float a = mb1[h];
      #pragma unroll
      for (int ec = 0; ec < 16; ec++) {
        float4 xe = ((const float4*)xr)[ec];
        float4 w  = ((const float4*)wr)[ec];
        a = fmaf(xe.x, w.x, a); a = fmaf(xe.y, w.y, a);
        a = fmaf(xe.z, w.z, a); a = fmaf(xe.w, w.w, a);
      }
      hid_f[idx] = fmaxf(a, 0.f);
    }
    __syncthreads();
    // I6b: slots = h' + hid @ mW2.T + mb2
    {
      int s = wv, d = lane;
      const float* hh = hid_f + s * 128;
      const float* wr = mW2 + d * 128;
      float a = mb2[d];
      #pragma unroll
      for (int ec = 0; ec < 32; ec++) {
        float4 xe = ((const float4*)hh)[ec];
        float4 w  = ((const float4*)wr)[ec];
        a = fmaf(xe.x, w.x, a); a = fmaf(xe.y, w.y, a);
        a = fmaf(xe.z, w.z, a); a = fmaf(xe.w, w.w, a);
      }
      sl_f[tid] = sl_f[tid] + a;
    }
    __syncthreads();
    // I7a: post hidden = relu(slots @ sr_W1.T + sr_b1)
    #pragma unroll
    for (int kk = 0; kk < 2; kk++) {
      int idx = tid + kk * 512;
      int s = idx >> 7, h = idx & 127;
      const float* xr = sl_f + s * 64;
      const float* wr = sr_W1 + h * 64;
      float a = sr_b1[h];
      #pragma unroll
      for (int ec = 0; ec < 16; ec++) {
        float4 xe = ((const float4*)xr)[ec];
        float4 w  = ((const float4*)wr)[ec];
        a = fmaf(xe.x, w.x, a); a = fmaf(xe.y, w.y, a);
        a = fmaf(xe.z, w.z, a); a = fmaf(xe.w, w.w, a);
      }
      hid_f[idx] = fmaxf(a, 0.f);
    }
    __syncthreads();
    // I7b: post = hid @ sr_W2.T + sr_b2
    #pragma unroll
    for (int kk = 0; kk < 2; kk++) {
      int idx = tid + kk * 512;
      int s = idx >> 7, o = idx & 127;
      const float* hh = hid_f + s * 128;
      const float* wr = sr_W2 + o * 128;
      float a = sr_b2[o];
      #pragma unroll
      for (int ec = 0; ec < 32; ec++) {
        float4 xe = ((const float4*)hh)[ec];
        float4 w  = ((const float4*)wr)[ec];
        a = fmaf(xe.x, w.x, a); a = fmaf(xe.y, w.y, a);
        a = fmaf(xe.z, w.z, a); a = fmaf(xe.w, w.w, a);
      }
      post_f[idx] = a;
    }
    __syncthreads();
    // I8: kl += 0.5 * sum_d [lv_pr - lv_po + (exp(lv_po) + (m_po-m_pr)^2) * exp(-lv_pr) - 1]
    {
      int s = wv, d = lane;
      float m_po = post_f[s * 128 + d],  lv_po = post_f[s * 128 + 64 + d];
      float m_pr = prior_f[s * 128 + d], lv_pr = prior_f[s * 128 + 64 + d];
      float dm = m_po - m_pr;
      float term = lv_pr - lv_po + (__expf(lv_po) + dm * dm) * __expf(-lv_pr) - 1.0f;
      float tsum = wredsum(term);
      if (lane == 0) kl_f[s] += 0.5f * tsum;
    }
    __syncthreads();
  }

  // ---- outputs: slots (B*NS*D f32), then kl (B*NS f32)
  out[(size_t)b * 512 + tid] = sl_f[tid];
  if (tid < 8) out[OUT_SLOTS_ + b * 8 + tid] = kl_f[tid];
}

extern "C" void kernel_launch(void* const* d_in, const int* in_sizes, int n_in,
                              void* d_out, int out_size, void* d_ws, size_t ws_size,
                              hipStream_t stream) {
  (void)in_sizes; (void)n_in; (void)out_size; (void)ws_size;
  const float* inputs      = (const float*)d_in[0];
  const float* slots0      = (const float*)d_in[1];
  const float* prior_slots = (const float*)d_in[2];
  const float* eps_noise   = (const float*)d_in[3];
  const float* ni_g  = (const float*)d_in[4];
  const float* ni_b  = (const float*)d_in[5];
  const float* npf_g = (const float*)d_in[6];
  const float* npf_b = (const float*)d_in[7];
  const float* Wq = (const float*)d_in[8];   const float* bq = (const float*)d_in[9];
  const float* Wk = (const float*)d_in[10];  const float* bk = (const float*)d_in[11];
  const float* Wv = (const float*)d_in[12];  const float* bv = (const float*)d_in[13];
  const float* sr_W1 = (const float*)d_in[14]; const float* sr_b1 = (const float*)d_in[15];
  const float* sr_W2 = (const float*)d_in[16]; const float* sr_b2 = (const float*)d_in[17];
  const float* pr_W1 = (const float*)d_in[18]; const float* pr_b1 = (const float*)d_in[19];
  const float* pr_W2 = (const float*)d_in[20]; const float* pr_b2 = (const float*)d_in[21];
  const float* gWih = (const float*)d_in[22]; const float* gWhh = (const float*)d_in[23];
  const float* gbih = (const float*)d_in[24]; const float* gbhh = (const float*)d_in[25];
  const float* mW1 = (const float*)d_in[26]; const float* mb1 = (const float*)d_in[27];
  const float* mW2 = (const float*)d_in[28]; const float* mb2 = (const float*)d_in[29];

  u16* K = (u16*)d_ws;
  u16* V = K + (size_t)B_ * N_ * D_;

  k_lnkv<<<dim3(4096), dim3(256), 0, stream>>>(inputs, ni_g, ni_b, Wk, bk, Wv, bv, K, V);

  const int SMEM = 86080;
  hipFuncSetAttribute((const void*)k_slot, hipFuncAttributeMaxDynamicSharedMemorySize, SMEM);
  k_slot<<<dim3(256), dim3(512), SMEM, stream>>>(
      K, V, slots0, prior_slots, eps_noise, npf_g, npf_b, Wq, bq,
      sr_W1, sr_b1, sr_W2, sr_b2, pr_W1, pr_b1, pr_W2, pr_b2,
      gWih, gWhh, gbih, gbhh, mW1, mb1, mW2, mb2, (float*)d_out);
}

// Round 2
// 2380.216 us; speedup vs baseline: 1.0286x; 1.0286x over previous
//
#include <hip/hip_runtime.h>
#include <hip/hip_bf16.h>
#include <cstdint>
#include <cstddef>

// SlotAttentionV2 forward, MI355X.
// K1 (MFMA): LN + K/V projection -> bf16 workspace. 64-row tiles, B-frags in regs.
// K2: one 1024-thread block per batch: reparam, 3 slot-attn iterations, GRU, MLP, KL.

#define B_   256
#define N_   4096
#define NS_  8
#define D_   64
#define EPS_   1e-8f
#define SCALE_ 0.125f
#define OUT_SLOTS_ (B_ * NS_ * D_)   // 131072
#define NTILES_ (B_ * N_ / 64)       // 16384

typedef unsigned short u16;
typedef unsigned int   u32;
typedef short s16x8 __attribute__((ext_vector_type(8)));
typedef float f32x4 __attribute__((ext_vector_type(4)));

__device__ inline float bf2f(u16 u) {
  union { u32 i; float f; } c; c.i = ((u32)u) << 16; return c.f;
}
__device__ inline u16 f2bf(float f) {
  union { u32 i; float f; } c; c.f = f;
  return (u16)((c.i + 0x7fffu + ((c.i >> 16) & 1u)) >> 16);
}
__device__ inline void bf2x2(u32 u, float& lo, float& hi) {
  union { u32 i; float f; } a, b;
  a.i = u << 16; b.i = u & 0xffff0000u;
  lo = a.f; hi = b.f;
}
__device__ inline float wredsum(float v) {
  #pragma unroll
  for (int o = 32; o; o >>= 1) v += __shfl_xor(v, o, 64);
  return v;
}

// ---------------- Kernel 1: LN(inputs) -> K, V (bf16) via MFMA ----------------
// Block: 256 thr (4 waves), 64-row tile per step, grid-stride over 16384 tiles.
// LDS: xhat bf16 [64][72] (pad 8 -> 2-way bank alias only).
__global__ __launch_bounds__(256, 3) void k_lnkv(
    const float* __restrict__ x,
    const float* __restrict__ ni_g, const float* __restrict__ ni_b,
    const float* __restrict__ Wk, const float* __restrict__ bk,
    const float* __restrict__ Wv, const float* __restrict__ bv,
    u16* __restrict__ K, u16* __restrict__ V)
{
  __shared__ u16 xsh[64 * 72];
  const int tid  = threadIdx.x;
  const int lane = tid & 63;
  const int w    = tid >> 6;      // wave 0..3 -> M-tile
  const int col  = lane & 15;     // MFMA col / B n-index
  const int kg   = lane >> 4;     // k-group 0..3

  // B-frags: [kstep][ntile]; nt 0-3 -> K outputs, 4-7 -> V outputs.
  s16x8 bf[2][8];
  float bias8[8];
  #pragma unroll
  for (int nt = 0; nt < 8; nt++) {
    const float* W = (nt < 4) ? Wk : Wv;
    const int n = (nt & 3) * 16 + col;
    bias8[nt] = (nt < 4) ? bk[n] : bv[n];
    #pragma unroll
    for (int ks = 0; ks < 2; ks++) {
      const float* src = W + n * 64 + ks * 32 + kg * 8;
      float4 w0 = *(const float4*)(src);
      float4 w1 = *(const float4*)(src + 4);
      union { s16x8 v; u16 u[8]; } pk;
      pk.u[0] = f2bf(w0.x); pk.u[1] = f2bf(w0.y);
      pk.u[2] = f2bf(w0.z); pk.u[3] = f2bf(w0.w);
      pk.u[4] = f2bf(w1.x); pk.u[5] = f2bf(w1.y);
      pk.u[6] = f2bf(w1.z); pk.u[7] = f2bf(w1.w);
      bf[ks][nt] = pk.v;
    }
  }

  // LN lane mapping: thread = (row xr, quarter xc), 16 contiguous cols each.
  const int xr = tid >> 2;
  const int xc = tid & 3;
  float4 g4[4], b4[4];
  #pragma unroll
  for (int j = 0; j < 4; j++) {
    g4[j] = *(const float4*)(ni_g + xc * 16 + j * 4);
    b4[j] = *(const float4*)(ni_b + xc * 16 + j * 4);
  }

  for (int tile = blockIdx.x; tile < NTILES_; tile += gridDim.x) {
    const float* Xrow = x + ((size_t)tile * 64 + xr) * 64 + xc * 16;
    float4 xv[4];
    #pragma unroll
    for (int j = 0; j < 4; j++) xv[j] = *(const float4*)(Xrow + j * 4);
    float s = 0.f;
    #pragma unroll
    for (int j = 0; j < 4; j++) s += xv[j].x + xv[j].y + xv[j].z + xv[j].w;
    s += __shfl_xor(s, 1, 64); s += __shfl_xor(s, 2, 64);
    const float m = s * (1.0f / 64.0f);
    float vs = 0.f;
    #pragma unroll
    for (int j = 0; j < 4; j++) {
      float a0 = xv[j].x - m, a1 = xv[j].y - m, a2 = xv[j].z - m, a3 = xv[j].w - m;
      vs += a0*a0 + a1*a1 + a2*a2 + a3*a3;
    }
    vs += __shfl_xor(vs, 1, 64); vs += __shfl_xor(vs, 2, 64);
    const float rs = rsqrtf(vs * (1.0f / 64.0f) + 1e-5f);
    // pack xhat -> LDS (2x b128)
    u32 pk[8];
    #pragma unroll
    for (int j = 0; j < 4; j++) {
      float h0 = (xv[j].x - m) * rs * g4[j].x + b4[j].x;
      float h1 = (xv[j].y - m) * rs * g4[j].y + b4[j].y;
      float h2 = (xv[j].z - m) * rs * g4[j].z + b4[j].z;
      float h3 = (xv[j].w - m) * rs * g4[j].w + b4[j].w;
      pk[j*2+0] = (u32)f2bf(h0) | ((u32)f2bf(h1) << 16);
      pk[j*2+1] = (u32)f2bf(h2) | ((u32)f2bf(h3) << 16);
    }
    u32* dst = (u32*)(xsh + xr * 72 + xc * 16);
    ((uint4*)dst)[0] = make_uint4(pk[0], pk[1], pk[2], pk[3]);
    ((uint4*)dst)[1] = make_uint4(pk[4], pk[5], pk[6], pk[7]);
    __syncthreads();

    // MFMA: wave w owns rows [w*16, w*16+16)
    const u16* ar = xsh + (w * 16 + col) * 72 + kg * 8;
    union { uint4 q; s16x8 v; } ua0, ua1;
    ua0.q = *(const uint4*)(ar);
    ua1.q = *(const uint4*)(ar + 32);
    f32x4 acc[8];
    #pragma unroll
    for (int nt = 0; nt < 8; nt++) {
      f32x4 a = {0.f, 0.f, 0.f, 0.f};
      a = __builtin_amdgcn_mfma_f32_16x16x32_bf16(ua0.v, bf[0][nt], a, 0, 0, 0);
      a = __builtin_amdgcn_mfma_f32_16x16x32_bf16(ua1.v, bf[1][nt], a, 0, 0, 0);
      acc[nt] = a;
    }
    const size_t rowb = (size_t)tile * 64 + w * 16 + kg * 4;
    #pragma unroll
    for (int nt = 0; nt < 8; nt++) {
      u16* out = (nt < 4) ? K : V;
      const int n = (nt & 3) * 16 + col;
      #pragma unroll
      for (int r = 0; r < 4; r++)
        out[(rowb + r) * 64 + n] = f2bf(acc[nt][r] + bias8[nt]);
    }
    __syncthreads();
  }
}

// ---------------- Kernel 2: block-per-batch slot attention (1024 thr) --------
// LDS (dynamic, 86080 B): attn u16[8][4096] | q f32[8][64] | sl | sp | upd |
// prior f32[8][128] | hid | post | Ssum[8] | kl[8]
__global__ __launch_bounds__(1024) void k_slot(
    const u16* __restrict__ K, const u16* __restrict__ V,
    const float* __restrict__ slots0, const float* __restrict__ prior_slots,
    const float* __restrict__ eps_noise,
    const float* __restrict__ npf_g, const float* __restrict__ npf_b,
    const float* __restrict__ Wq, const float* __restrict__ bq,
    const float* __restrict__ sr_W1, const float* __restrict__ sr_b1,
    const float* __restrict__ sr_W2, const float* __restrict__ sr_b2,
    const float* __restrict__ pr_W1, const float* __restrict__ pr_b1,
    const float* __restrict__ pr_W2, const float* __restrict__ pr_b2,
    const float* __restrict__ gWih, const float* __restrict__ gWhh,
    const float* __restrict__ gbih, const float* __restrict__ gbhh,
    const float* __restrict__ mW1, const float* __restrict__ mb1,
    const float* __restrict__ mW2, const float* __restrict__ mb2,
    float* __restrict__ out)
{
  extern __shared__ char smem[];
  u16*   attn_u  = (u16*)smem;                  // 65536
  float* q_f     = (float*)(smem + 65536);      // 2048
  float* sl_f    = (float*)(smem + 67584);      // 2048
  float* sp_f    = (float*)(smem + 69632);      // 2048
  float* upd_f   = (float*)(smem + 71680);      // 2048
  float* prior_f = (float*)(smem + 73728);      // 4096
  float* hid_f   = (float*)(smem + 77824);      // 4096
  float* post_f  = (float*)(smem + 81920);      // 4096
  float* Ssum    = (float*)(smem + 86016);      // 32
  float* kl_f    = (float*)(smem + 86048);      // 32

  const int tid  = threadIdx.x;    // 0..1023
  const int wv   = tid >> 6;       // wave 0..15
  const int lane = tid & 63;
  const int b    = blockIdx.x;
  const u16* Kb = K + (size_t)b * (N_ * 64);
  const u16* Vb = V + (size_t)b * (N_ * 64);

  // ---- P0.1: slots load + prior hidden = relu(prior_slots @ pr_W1.T + pr_b1)
  if (tid < 512) sl_f[tid] = slots0[(size_t)b * 512 + tid];
  {
    int s = tid >> 7, h = tid & 127;
    const float* xr = prior_slots + ((size_t)b * 8 + s) * 64;
    const float* wr = pr_W1 + h * 64;
    float a = pr_b1[h];
    #pragma unroll
    for (int ec = 0; ec < 16; ec++) {
      float4 xe = ((const float4*)xr)[ec];
      float4 w  = ((const float4*)wr)[ec];
      a = fmaf(xe.x, w.x, a); a = fmaf(xe.y, w.y, a);
      a = fmaf(xe.z, w.z, a); a = fmaf(xe.w, w.w, a);
    }
    hid_f[tid] = fmaxf(a, 0.f);
  }
  __syncthreads();
  // ---- P0.2: prior = hid @ pr_W2.T + pr_b2
  {
    int s = tid >> 7, o = tid & 127;
    const float* hh = hid_f + s * 128;
    const float* wr = pr_W2 + o * 128;
    float a = pr_b2[o];
    #pragma unroll
    for (int ec = 0; ec < 32; ec++) {
      float4 xe = ((const float4*)hh)[ec];
      float4 w  = ((const float4*)wr)[ec];
      a = fmaf(xe.x, w.x, a); a = fmaf(xe.y, w.y, a);
      a = fmaf(xe.z, w.z, a); a = fmaf(xe.w, w.w, a);
    }
    prior_f[tid] = a;
  }
  __syncthreads();
  // ---- P0.3: sms hidden = relu(slots @ sr_W1.T + sr_b1)
  {
    int s = tid >> 7, h = tid & 127;
    const float* xr = sl_f + s * 64;
    const float* wr = sr_W1 + h * 64;
    float a = sr_b1[h];
    #pragma unroll
    for (int ec = 0; ec < 16; ec++) {
      float4 xe = ((const float4*)xr)[ec];
      float4 w  = ((const float4*)wr)[ec];
      a = fmaf(xe.x, w.x, a); a = fmaf(xe.y, w.y, a);
      a = fmaf(xe.z, w.z, a); a = fmaf(xe.w, w.w, a);
    }
    hid_f[tid] = fmaxf(a, 0.f);
  }
  __syncthreads();
  // ---- P0.4: sms = hid @ sr_W2.T + sr_b2 -> post
  {
    int s = tid >> 7, o = tid & 127;
    const float* hh = hid_f + s * 128;
    const float* wr = sr_W2 + o * 128;
    float a = sr_b2[o];
    #pragma unroll
    for (int ec = 0; ec < 32; ec++) {
      float4 xe = ((const float4*)hh)[ec];
      float4 w  = ((const float4*)wr)[ec];
      a = fmaf(xe.x, w.x, a); a = fmaf(xe.y, w.y, a);
      a = fmaf(xe.z, w.z, a); a = fmaf(xe.w, w.w, a);
    }
    post_f[tid] = a;
  }
  __syncthreads();
  // ---- P0.5: reparam
  if (tid < 512) {
    int s = tid >> 6, d = tid & 63;
    float mu = post_f[s * 128 + d];
    float lv = post_f[s * 128 + 64 + d];
    sl_f[tid] = eps_noise[(size_t)b * 512 + tid] * __expf(0.5f * lv) + mu;
  }
  if (tid < 8) kl_f[tid] = 0.f;
  __syncthreads();

  // ---- iterations ----
  #pragma unroll 1
  for (int it = 0; it < 3; it++) {
    // I1: snapshot, zero, q = slots @ Wq.T + bq
    if (tid < 512) {
      sp_f[tid]  = sl_f[tid];
      upd_f[tid] = 0.f;
      int s = tid >> 6, d = tid & 63;
      const float* xr = sl_f + s * 64;
      const float* wr = Wq + d * 64;
      float a = bq[d];
      #pragma unroll
      for (int ec = 0; ec < 16; ec++) {
        float4 xe = ((const float4*)xr)[ec];
        float4 w  = ((const float4*)wr)[ec];
        a = fmaf(xe.x, w.x, a); a = fmaf(xe.y, w.y, a);
        a = fmaf(xe.z, w.z, a); a = fmaf(xe.w, w.w, a);
      }
      q_f[tid] = a;
    }
    if (tid < 8) Ssum[tid] = 0.f;
    __syncthreads();

    // I2: pass A — 4 px/thread (2 steps x 2 px), packed-K unpack on the fly
    float s_loc[8];
    #pragma unroll
    for (int i = 0; i < 8; i++) s_loc[i] = 0.f;
    #pragma unroll 1
    for (int st = 0; st < 2; st++) {
      const int j1 = st * 2048 + tid;
      const int j2 = j1 + 1024;
      uint4 kr1[8], kr2[8];
      const uint4* p1 = (const uint4*)(Kb + (size_t)j1 * 64);
      const uint4* p2 = (const uint4*)(Kb + (size_t)j2 * 64);
      #pragma unroll
      for (int c = 0; c < 8; c++) { kr1[c] = p1[c]; kr2[c] = p2[c]; }
      float d1[8], d2[8];
      #pragma unroll
      for (int i = 0; i < 8; i++) {
        const float4* qr = (const float4*)(q_f + i * 64);
        float a1 = 0.f, a2 = 0.f;
        #pragma unroll
        for (int c = 0; c < 8; c++) {
          float4 qa = qr[c * 2], qb = qr[c * 2 + 1];
          float x0,x1,x2,x3,x4,x5,x6,x7;
          bf2x2(kr1[c].x, x0, x1); bf2x2(kr1[c].y, x2, x3);
          bf2x2(kr1[c].z, x4, x5); bf2x2(kr1[c].w, x6, x7);
          a1 = fmaf(qa.x,x0,a1); a1 = fmaf(qa.y,x1,a1);
          a1 = fmaf(qa.z,x2,a1); a1 = fmaf(qa.w,x3,a1);
          a1 = fmaf(qb.x,x4,a1); a1 = fmaf(qb.y,x5,a1);
          a1 = fmaf(qb.z,x6,a1); a1 = fmaf(qb.w,x7,a1);
          bf2x2(kr2[c].x, x0, x1); bf2x2(kr2[c].y, x2, x3);
          bf2x2(kr2[c].z, x4, x5); bf2x2(kr2[c].w, x6, x7);
          a2 = fmaf(qa.x,x0,a2); a2 = fmaf(qa.y,x1,a2);
          a2 = fmaf(qa.z,x2,a2); a2 = fmaf(qa.w,x3,a2);
          a2 = fmaf(qb.x,x4,a2); a2 = fmaf(qb.y,x5,a2);
          a2 = fmaf(qb.z,x6,a2); a2 = fmaf(qb.w,x7,a2);
        }
        d1[i] = a1 * SCALE_; d2[i] = a2 * SCALE_;
      }
      float m1 = d1[0], m2 = d2[0];
      #pragma unroll
      for (int i = 1; i < 8; i++) { m1 = fmaxf(m1, d1[i]); m2 = fmaxf(m2, d2[i]); }
      float sm1 = 0.f, sm2 = 0.f;
      #pragma unroll
      for (int i = 0; i < 8; i++) {
        d1[i] = __expf(d1[i] - m1); sm1 += d1[i];
        d2[i] = __expf(d2[i] - m2); sm2 += d2[i];
      }
      const float r1 = 1.0f / sm1, r2 = 1.0f / sm2;
      #pragma unroll
      for (int i = 0; i < 8; i++) {
        float a1 = fmaf(d1[i], r1, EPS_);
        float a2 = fmaf(d2[i], r2, EPS_);
        s_loc[i] += a1 + a2;
        attn_u[i * 4096 + j1] = f2bf(a1);
        attn_u[i * 4096 + j2] = f2bf(a2);
      }
    }
    #pragma unroll
    for (int i = 0; i < 8; i++) {
      float v = wredsum(s_loc[i]);
      if (lane == 0) atomicAdd(&Ssum[i], v);
    }
    __syncthreads();

    // I3: pass B — lane owns (px-group of 8, 8-dim chunk); uint4 V loads.
    {
      const int px_off = lane >> 3;        // 0..7
      const int dc = (lane & 7) * 8;       // dim chunk base
      float u[8][8];
      #pragma unroll
      for (int i = 0; i < 8; i++)
        #pragma unroll
        for (int dd = 0; dd < 8; dd++) u[i][dd] = 0.f;
      const int jbase = wv * 256;
      #pragma unroll 2
      for (int st = 0; st < 32; st++) {
        const int j = jbase + st * 8 + px_off;
        uint4 v4 = *(const uint4*)(Vb + (size_t)j * 64 + dc);
        float vv[8];
        bf2x2(v4.x, vv[0], vv[1]); bf2x2(v4.y, vv[2], vv[3]);
        bf2x2(v4.z, vv[4], vv[5]); bf2x2(v4.w, vv[6], vv[7]);
        #pragma unroll
        for (int i = 0; i < 8; i++) {
          float a = bf2f(attn_u[i * 4096 + j]);
          #pragma unroll
          for (int dd = 0; dd < 8; dd++) u[i][dd] = fmaf(a, vv[dd], u[i][dd]);
        }
      }
      #pragma unroll
      for (int i = 0; i < 8; i++)
        #pragma unroll
        for (int dd = 0; dd < 8; dd++)
          atomicAdd(upd_f + i * 64 + dc + dd, u[i][dd]);
    }
    __syncthreads();

    // I4+I5: GRU (1/S folded) + LN of GRU output
    if (tid < 512) {
      int s = tid >> 6, d = tid & 63;
      const float* ur  = upd_f + s * 64;
      const float* hr  = sp_f + s * 64;
      const float* wi0 = gWih + d * 64;
      const float* wi1 = gWih + (64 + d) * 64;
      const float* wi2 = gWih + (128 + d) * 64;
      const float* wh0 = gWhh + d * 64;
      const float* wh1 = gWhh + (64 + d) * 64;
      const float* wh2 = gWhh + (128 + d) * 64;
      float air=0.f, aiz=0.f, ain=0.f, ahr=0.f, ahz=0.f, ahn=0.f;
      #pragma unroll
      for (int ec = 0; ec < 16; ec++) {
        float4 xe = ((const float4*)ur)[ec];
        float4 he = ((const float4*)hr)[ec];
        float4 w;
        w = ((const float4*)wi0)[ec];
        air = fmaf(xe.x,w.x,air); air = fmaf(xe.y,w.y,air);
        air = fmaf(xe.z,w.z,air); air = fmaf(xe.w,w.w,air);
        w = ((const float4*)wi1)[ec];
        aiz = fmaf(xe.x,w.x,aiz); aiz = fmaf(xe.y,w.y,aiz);
        aiz = fmaf(xe.z,w.z,aiz); aiz = fmaf(xe.w,w.w,aiz);
        w = ((const float4*)wi2)[ec];
        ain = fmaf(xe.x,w.x,ain); ain = fmaf(xe.y,w.y,ain);
        ain = fmaf(xe.z,w.z,ain); ain = fmaf(xe.w,w.w,ain);
        w = ((const float4*)wh0)[ec];
        ahr = fmaf(he.x,w.x,ahr); ahr = fmaf(he.y,w.y,ahr);
        ahr = fmaf(he.z,w.z,ahr); ahr = fmaf(he.w,w.w,ahr);
        w = ((const float4*)wh1)[ec];
        ahz = fmaf(he.x,w.x,ahz); ahz = fmaf(he.y,w.y,ahz);
        ahz = fmaf(he.z,w.z,ahz); ahz = fmaf(he.w,w.w,ahz);
        w = ((const float4*)wh2)[ec];
        ahn = fmaf(he.x,w.x,ahn); ahn = fmaf(he.y,w.y,ahn);
        ahn = fmaf(he.z,w.z,ahn); ahn = fmaf(he.w,w.w,ahn);
      }
      float sinv = 1.0f / Ssum[s];
      float rr = 1.0f / (1.0f + __expf(-(air * sinv + gbih[d]      + ahr + gbhh[d])));
      float zz = 1.0f / (1.0f + __expf(-(aiz * sinv + gbih[64 + d] + ahz + gbhh[64 + d])));
      float nn = tanhf(ain * sinv + gbih[128 + d] + rr * (ahn + gbhh[128 + d]));
      float hnew = (1.0f - zz) * nn + zz * sp_f[tid];
      sl_f[tid] = hnew;
      float mm = wredsum(hnew) * (1.0f / 64.0f);
      float cc = hnew - mm;
      float va = wredsum(cc * cc) * (1.0f / 64.0f);
      q_f[tid] = cc * rsqrtf(va + 1e-5f) * npf_g[d] + npf_b[d];  // reuse q
    }
    __syncthreads();

    // I6a: mlp hidden
    {
      int s = tid >> 7, h = tid & 127;
      const float* xr = q_f + s * 64;
      const float* wr = mW1 + h * 64;
      float a = mb1[h];
      #pragma unroll
      for (int ec = 0; ec < 16; ec++) {
        float4 xe = ((const float4*)xr)[ec];
        float4 w  = ((const float4*)wr)[ec];
        a = fmaf(xe.x, w.x, a); a = fmaf(xe.y, w.y, a);
        a = fmaf(xe.z, w.z, a); a = fmaf(xe.w, w.w, a);
      }
      hid_f[tid] = fmaxf(a, 0.f);
    }
    __syncthreads();
    // I6b: slots += mlp out
    if (tid < 512) {
      int s = tid >> 6, d = tid & 63;
      const float* hh = hid_f + s * 128;
      const float* wr = mW2 + d * 128;
      float a = mb2[d];
      #pragma unroll
      for (int ec = 0; ec < 32; ec++) {
        float4 xe = ((const float4*)hh)[ec];
        float4 w  = ((const float4*)wr)[ec];
        a = fmaf(xe.x, w.x, a); a = fmaf(xe.y, w.y, a);
        a = fmaf(xe.z, w.z, a); a = fmaf(xe.w, w.w, a);
      }
      sl_f[tid] = sl_f[tid] + a;
    }
    __syncthreads();
    // I7a: post hidden
    {
      int s = tid >> 7, h = tid & 127;
      const float* xr = sl_f + s * 64;
      const float* wr = sr_W1 + h * 64;
      float a = sr_b1[h];
      #pragma unroll
      for (int ec = 0; ec < 16; ec++) {
        float4 xe = ((const float4*)xr)[ec];
        float4 w  = ((const float4*)wr)[ec];
        a = fmaf(xe.x, w.x, a); a = fmaf(xe.y, w.y, a);
        a = fmaf(xe.z, w.z, a); a = fmaf(xe.w, w.w, a);
      }
      hid_f[tid] = fmaxf(a, 0.f);
    }
    __syncthreads();
    // I7b: post
    {
      int s = tid >> 7, o = tid & 127;
      const float* hh = hid_f + s * 128;
      const float* wr = sr_W2 + o * 128;
      float a = sr_b2[o];
      #pragma unroll
      for (int ec = 0; ec < 32; ec++) {
        float4 xe = ((const float4*)hh)[ec];
        float4 w  = ((const float4*)wr)[ec];
        a = fmaf(xe.x, w.x, a); a = fmaf(xe.y, w.y, a);
        a = fmaf(xe.z, w.z, a); a = fmaf(xe.w, w.w, a);
      }
      post_f[tid] = a;
    }
    __syncthreads();
    // I8: KL accumulate
    if (tid < 512) {
      int s = tid >> 6, d = tid & 63;
      float m_po = post_f[s * 128 + d],  lv_po = post_f[s * 128 + 64 + d];
      float m_pr = prior_f[s * 128 + d], lv_pr = prior_f[s * 128 + 64 + d];
      float dm = m_po - m_pr;
      float term = lv_pr - lv_po + (__expf(lv_po) + dm * dm) * __expf(-lv_pr) - 1.0f;
      float tsum = wredsum(term);
      if (lane == 0) kl_f[s] += 0.5f * tsum;
    }
    __syncthreads();
  }

  if (tid < 512) out[(size_t)b * 512 + tid] = sl_f[tid];
  if (tid < 8)   out[OUT_SLOTS_ + b * 8 + tid] = kl_f[tid];
}

extern "C" void kernel_launch(void* const* d_in, const int* in_sizes, int n_in,
                              void* d_out, int out_size, void* d_ws, size_t ws_size,
                              hipStream_t stream) {
  (void)in_sizes; (void)n_in; (void)out_size; (void)ws_size;
  const float* inputs      = (const float*)d_in[0];
  const float* slots0      = (const float*)d_in[1];
  const float* prior_slots = (const float*)d_in[2];
  const float* eps_noise   = (const float*)d_in[3];
  const float* ni_g  = (const float*)d_in[4];
  const float* ni_b  = (const float*)d_in[5];
  const float* npf_g = (const float*)d_in[6];
  const float* npf_b = (const float*)d_in[7];
  const float* Wq = (const float*)d_in[8];   const float* bq = (const float*)d_in[9];
  const float* Wk = (const float*)d_in[10];  const float* bk = (const float*)d_in[11];
  const float* Wv = (const float*)d_in[12];  const float* bv = (const float*)d_in[13];
  const float* sr_W1 = (const float*)d_in[14]; const float* sr_b1 = (const float*)d_in[15];
  const float* sr_W2 = (const float*)d_in[16]; const float* sr_b2 = (const float*)d_in[17];
  const float* pr_W1 = (const float*)d_in[18]; const float* pr_b1 = (const float*)d_in[19];
  const float* pr_W2 = (const float*)d_in[20]; const float* pr_b2 = (const float*)d_in[21];
  const float* gWih = (const float*)d_in[22]; const float* gWhh = (const float*)d_in[23];
  const float* gbih = (const float*)d_in[24]; const float* gbhh = (const float*)d_in[25];
  const float* mW1 = (const float*)d_in[26]; const float* mb1 = (const float*)d_in[27];
  const float* mW2 = (const float*)d_in[28]; const float* mb2 = (const float*)d_in[29];

  u16* K = (u16*)d_ws;
  u16* V = K + (size_t)B_ * N_ * D_;

  k_lnkv<<<dim3(1024), dim3(256), 0, stream>>>(inputs, ni_g, ni_b, Wk, bk, Wv, bv, K, V);

  const int SMEM = 86080;
  hipFuncSetAttribute((const void*)k_slot, hipFuncAttributeMaxDynamicSharedMemorySize, SMEM);
  k_slot<<<dim3(256), dim3(1024), SMEM, stream>>>(
      K, V, slots0, prior_slots, eps_noise, npf_g, npf_b, Wq, bq,
      sr_W1, sr_b1, sr_W2, sr_b2, pr_W1, pr_b1, pr_W2, pr_b2,
      gWih, gWhh, gbih, gbhh, mW1, mb1, mW2, mb2, (float*)d_out);
}